// Round 1
// baseline (212.687 us; speedup 1.0000x reference)
//
#include <hip/hip_runtime.h>

// ---------------------------------------------------------------------------
// ImprovedEdgeGNN forward — MI355X
// Sizes: B=8, N=512, D=512, H=256, E=32, C=2
// out layout: [0:16) logits [8,2], [16] total_loss, [17:17+8*512*512) wadj
// R7: latency polish on the ~30us of kernel time (dur is ~172us harness
//     poison at HBM roofline — fillBufferAligned at 75-78% peak, 4x43us):
//     - classifier: wave-parallel LN stats, fused 1-pass spectral-norm
//       reduction (sigma from {Sum v^2, Sum v*W0, Sum v*W1}), 16x16-group
//       logits reduce. ~36 barriers -> 4.
//     - gemm_pool: softmax via __shfl_xor (2 barriers, was ~18 tree steps).
//     - edge_kernel: one expf per edge (sigma(logA+C) = 1/(1+K*e)).
//     Decision rule: if this moves <1.5%, remaining dur is harness reset
//     overhead -> declare roofline.
// ---------------------------------------------------------------------------

#define Bsz 8
#define Nn  512
#define Dd  512
#define Hh  256
#define Ee  32

// ws offsets (floats)
#define WS_NFCPK  0L          // nfc bf16 k-packed [8][64oct][256c][8] = 524,288 f
#define WS_E1     524288L     // [4096][32] f32 (be folded)            131,072 f
#define WS_E2     655360L     // [4096][32] f32                        131,072 f
#define WS_WADJB  786432L     // wadj bf16 [8][512][512]             1,048,576 f
#define WS_RS     1835008L    // [4096] raw row sums (= imp)
#define WS_L0     1839104L    // [8]
#define WS_GR     1839112L    // [8][256]
#define WS_WABPK  1841160L    // [Wa|Wb] bf16 pk [64kq][64n][8]         16,384 f
#define WS_WCPK   1857544L    // Wconv bf16 pk [64kq][256n][8]          65,536 f

typedef __bf16 bf16x8 __attribute__((ext_vector_type(8)));
typedef float  f32x4  __attribute__((ext_vector_type(4)));

__device__ inline ushort f2bf(float f) {
  union { float f; unsigned u; } c; c.f = f;
  return (ushort)((c.u + 0x7fffu + ((c.u >> 16) & 1u)) >> 16);
}

// ---------------------------------------------------------------------------
// K0: pack weights to bf16 k-packed granules [(K/8)][N][8].
__global__ __launch_bounds__(256) void pack_weights(
    const float* __restrict__ Wconv, const float* __restrict__ Wa,
    const float* __restrict__ Wb, ushort* __restrict__ wcpk,
    ushort* __restrict__ wabpk)
{
  const int g = blockIdx.x*256 + threadIdx.x;
  if (g < 16384) {                       // Wconv granules
    const int kq = g >> 8, n = g & 255;
    ushort tmp[8];
    #pragma unroll
    for (int j = 0; j < 8; ++j) tmp[j] = f2bf(Wconv[(kq*8 + j)*Hh + n]);
    *(uint4*)(wcpk + (long)g*8) = *(uint4*)tmp;
  } else if (g < 16384 + 4096) {         // Wa|Wb granules
    const int gg = g - 16384;
    const int kq = gg >> 6, n = gg & 63;
    const float* W = (n < 32) ? Wa : Wb;
    const int e = n & 31;
    ushort tmp[8];
    #pragma unroll
    for (int j = 0; j < 8; ++j) tmp[j] = f2bf(W[(kq*8 + j)*Ee + e]);
    *(uint4*)(wabpk + (long)gg*8) = *(uint4*)tmp;
  }
}

// ---------------------------------------------------------------------------
// K1: fused normalize + e1|e2 + nfc = nf@Wconv. 256 blocks x 16 rows.
// Double-buffered B staging: one barrier per K-iter.
__global__ __launch_bounds__(256) void norm_e12_nfc(
    const float* __restrict__ nfeat, const ushort* __restrict__ wabpk,
    const ushort* __restrict__ wcpk, const float* __restrict__ be,
    ushort* __restrict__ nfcpk, float* __restrict__ e1, float* __restrict__ e2,
    float* __restrict__ row_sum, float* __restrict__ gr,
    float* __restrict__ l0_sum)
{
  const int blk = blockIdx.x;
  const int r0 = blk*16;               // global row base (b*512 + local)
  const int b = r0 >> 9;
  const int t = threadIdx.x;
  const int r = t >> 4;                // local row 0..15
  const int seg = t & 15;              // 32-col segment

  __shared__ ushort As[(63*17 + 15 + 1)*8];   // granule (kq*17 + row)*8
  __shared__ ushort BsA[2][4*64*8];           // Wa|Wb tile granules (dbuf)
  __shared__ ushort BsC[2][4*256*8];          // Wconv tile granules (dbuf)

  // ---- phase 1: load 32 f32/thread, row norm, bf16 granules to LDS ----
  float4 v[8];
  const float* src = nfeat + (long)(r0 + r)*Dd + seg*32;
  #pragma unroll
  for (int i = 0; i < 8; ++i) v[i] = *(const float4*)(src + i*4);
  float s = 0.f;
  #pragma unroll
  for (int i = 0; i < 8; ++i)
    s += v[i].x*v[i].x + v[i].y*v[i].y + v[i].z*v[i].z + v[i].w*v[i].w;
  #pragma unroll
  for (int m = 1; m < 16; m <<= 1) s += __shfl_xor(s, m, 16);
  const float sc = 1.f / fmaxf(sqrtf(s), 1e-12f);
  #pragma unroll
  for (int q = 0; q < 4; ++q) {
    ushort tmp[8];
    const float4 a = v[2*q], bq = v[2*q+1];
    tmp[0]=f2bf(a.x*sc);  tmp[1]=f2bf(a.y*sc);  tmp[2]=f2bf(a.z*sc);  tmp[3]=f2bf(a.w*sc);
    tmp[4]=f2bf(bq.x*sc); tmp[5]=f2bf(bq.y*sc); tmp[6]=f2bf(bq.z*sc); tmp[7]=f2bf(bq.w*sc);
    *(uint4*)(As + ((seg*4 + q)*17 + r)*8) = *(uint4*)tmp;
  }
  if (t < 16) row_sum[r0 + t] = 0.f;
  if (blk == 0) {
    for (int p = t; p < Bsz*Hh; p += 256) gr[p] = 0.f;
    if (t == 0) *l0_sum = 0.f;
  }

  // ---- phase 2: MFMA over K, double-buffered weight staging ----
  const int lane = t & 63, l15 = lane & 15, quad = lane >> 4;
  const int w = t >> 6;                  // wave id 0..3
  const int abq = t >> 6, abn = t & 63;  // Wa|Wb staging map

  f32x4 acc_e = {0.f, 0.f, 0.f, 0.f};
  f32x4 acc_c[4];
  #pragma unroll
  for (int j = 0; j < 4; ++j) acc_c[j] = (f32x4){0.f,0.f,0.f,0.f};

  // stage k=0 into buf 0, then prefetch k=32 into regs
  uint4 pab = *(const uint4*)(wabpk + ((long)abq*64 + abn)*8);
  uint4 pc[4];
  #pragma unroll
  for (int p = 0; p < 4; ++p) {
    const int g = t + p*256;
    pc[p] = *(const uint4*)(wcpk + ((long)(g >> 8)*256 + (g & 255))*8);
  }
  *(uint4*)(BsA[0] + (abq*64 + abn)*8) = pab;
  #pragma unroll
  for (int p = 0; p < 4; ++p) {
    const int g = t + p*256;
    *(uint4*)(BsC[0] + ((g >> 8)*256 + (g & 255))*8) = pc[p];
  }
  {
    pab = *(const uint4*)(wabpk + ((long)(4 + abq)*64 + abn)*8);
    #pragma unroll
    for (int p = 0; p < 4; ++p) {
      const int g = t + p*256;
      pc[p] = *(const uint4*)(wcpk + ((long)(4 + (g >> 8))*256 + (g & 255))*8);
    }
  }

  for (int k0 = 0; k0 < 512; k0 += 32) {
    const int pb = (k0 >> 5) & 1;
    __syncthreads();                     // buf[pb] writes visible; old reads done
    if (k0 + 32 < 512) {
      // stage k0+32 into buf[1-pb] (regs hold it), then prefetch k0+64
      *(uint4*)(BsA[1-pb] + (abq*64 + abn)*8) = pab;
      #pragma unroll
      for (int p = 0; p < 4; ++p) {
        const int g = t + p*256;
        *(uint4*)(BsC[1-pb] + ((g >> 8)*256 + (g & 255))*8) = pc[p];
      }
      if (k0 + 64 < 512) {
        const int kb = (k0 + 64) >> 3;
        pab = *(const uint4*)(wabpk + ((long)(kb + abq)*64 + abn)*8);
        #pragma unroll
        for (int p = 0; p < 4; ++p) {
          const int g = t + p*256;
          pc[p] = *(const uint4*)(wcpk + ((long)(kb + (g >> 8))*256 + (g & 255))*8);
        }
      }
    }
    const bf16x8 af = *(const bf16x8*)(As + (((k0 >> 3) + quad)*17 + l15)*8);
    const bf16x8 bfa = *(const bf16x8*)(BsA[pb] + (quad*64 + w*16 + l15)*8);
    acc_e = __builtin_amdgcn_mfma_f32_16x16x32_bf16(af, bfa, acc_e, 0, 0, 0);
    #pragma unroll
    for (int fn = 0; fn < 4; ++fn) {
      const bf16x8 bfc = *(const bf16x8*)(BsC[pb] + (quad*256 + w*64 + fn*16 + l15)*8);
      acc_c[fn] = __builtin_amdgcn_mfma_f32_16x16x32_bf16(af, bfc, acc_c[fn], 0, 0, 0);
    }
  }

  // ---- epilogue A: e1|e2 (wave w -> cols w*16..+15) ----
  {
    const int col = w*16 + l15;
    #pragma unroll
    for (int rr = 0; rr < 4; ++rr) {
      const int row = r0 + quad*4 + rr;
      if (col < 32) e1[(long)row*Ee + col] = acc_e[rr] + be[col];
      else          e2[(long)row*Ee + (col - 32)] = acc_e[rr];
    }
  }

  // ---- epilogue B: nfc -> k-packed global via LDS transpose ----
  __syncthreads();                       // all frag reads of BsC done
  ushort* tile = BsC[0];                 // [16][260] bf16
  #pragma unroll
  for (int fn = 0; fn < 4; ++fn) {
    const int col = w*64 + fn*16 + l15;
    #pragma unroll
    for (int rr = 0; rr < 4; ++rr)
      tile[(quad*4 + rr)*260 + col] = f2bf(acc_c[fn][rr]);
  }
  __syncthreads();
  #pragma unroll
  for (int p = 0; p < 2; ++p) {
    const int g = t + p*256;
    const int oct = g >> 8, c = g & 255;
    ushort tmp[8];
    #pragma unroll
    for (int j = 0; j < 8; ++j) tmp[j] = tile[(oct*8 + j)*260 + c];
    const long og = ((r0 & 511) >> 3) + oct;     // node-octet within batch
    *(uint4*)(nfcpk + ((long)b*16384 + og*256 + c)*8) = *(uint4*)tmp;
  }
}

// ---------------------------------------------------------------------------
// K2: tiled edge scoring. Block = (b, 32-row i-tile, 128-col j-tile).
// R7: single expf per edge — sigma(logA) = 1/(1+e), sigma(logA+C) = 1/(1+K*e)
//     with e = expf(-logA), K = exp(-1.58261088) = 0.20543832.
__global__ __launch_bounds__(256) void edge_kernel(
    const float* __restrict__ e1, const float* __restrict__ e2,
    const float* __restrict__ W2e, const float* __restrict__ b2e,
    const float* __restrict__ adjs, float* __restrict__ out_wadj,
    ushort* __restrict__ wadj_b, float* __restrict__ row_sum,
    float* __restrict__ l0_sum)
{
  const int b  = blockIdx.z;
  const int i0 = blockIdx.y * 32;
  const int j0 = blockIdx.x * 128;
  const int t  = threadIdx.x;

  __shared__ float e2s[32*132];

  #pragma unroll
  for (int itr = 0; itr < 4; ++itr) {
    const int idx = t + itr*256;
    const int kq = idx & 7, jg = idx >> 3;
    const float4 v = *(const float4*)(e2 + ((long)(b*Nn + j0 + jg))*Ee + kq*4);
    e2s[(kq*4+0)*132 + jg] = v.x;
    e2s[(kq*4+1)*132 + jg] = v.y;
    e2s[(kq*4+2)*132 + jg] = v.z;
    e2s[(kq*4+3)*132 + jg] = v.w;
  }

  const int pair  = t >> 4;
  const int jslot = t & 15;
  const int ia = i0 + pair*2;
  const int ib = ia + 1;
  const int ja = jslot*4;
  const int jb = ja + 64;

  float e1af[32], e1bf[32], w2f[32];
  #pragma unroll
  for (int q = 0; q < 8; ++q) {
    *(float4*)(&e1af[q*4]) = *(const float4*)(e1 + ((long)(b*Nn + ia))*Ee + q*4);
    *(float4*)(&e1bf[q*4]) = *(const float4*)(e1 + ((long)(b*Nn + ib))*Ee + q*4);
    *(float4*)(&w2f[q*4])  = *(const float4*)(W2e + q*4);
  }
  const float b2 = b2e[0];
  __syncthreads();

  float acc[2][8] = {};
  #pragma unroll
  for (int k = 0; k < 32; ++k) {
    const float4 va = *(const float4*)(e2s + k*132 + ja);
    const float4 vb = *(const float4*)(e2s + k*132 + jb);
    const float w = w2f[k];
    const float ea = e1af[k], eb = e1bf[k];
    acc[0][0] += fmaxf(ea+va.x, 0.f)*w;
    acc[0][1] += fmaxf(ea+va.y, 0.f)*w;
    acc[0][2] += fmaxf(ea+va.z, 0.f)*w;
    acc[0][3] += fmaxf(ea+va.w, 0.f)*w;
    acc[0][4] += fmaxf(ea+vb.x, 0.f)*w;
    acc[0][5] += fmaxf(ea+vb.y, 0.f)*w;
    acc[0][6] += fmaxf(ea+vb.z, 0.f)*w;
    acc[0][7] += fmaxf(ea+vb.w, 0.f)*w;
    acc[1][0] += fmaxf(eb+va.x, 0.f)*w;
    acc[1][1] += fmaxf(eb+va.y, 0.f)*w;
    acc[1][2] += fmaxf(eb+va.z, 0.f)*w;
    acc[1][3] += fmaxf(eb+va.w, 0.f)*w;
    acc[1][4] += fmaxf(eb+vb.x, 0.f)*w;
    acc[1][5] += fmaxf(eb+vb.y, 0.f)*w;
    acc[1][6] += fmaxf(eb+vb.z, 0.f)*w;
    acc[1][7] += fmaxf(eb+vb.w, 0.f)*w;
  }

  float rs[2] = {0.f, 0.f};
  float l0acc = 0.f;
  #pragma unroll
  for (int ii = 0; ii < 2; ++ii) {
    const int i = (ii == 0) ? ia : ib;
    const float* arow = adjs     + ((long)(b*Nn + i))*Nn + j0;
    ushort* bwrow     = wadj_b   + ((long)(b*Nn + i))*Nn + j0;
    float* outrow     = out_wadj + ((long)(b*Nn + i))*Nn + j0;
    #pragma unroll
    for (int h2 = 0; h2 < 2; ++h2) {
      const int jl = (h2 == 0) ? ja : jb;
      const float4 av = *(const float4*)(arow + jl);
      float wv[4];
      #pragma unroll
      for (int c = 0; c < 4; ++c) {
        const float logA = acc[ii][h2*4 + c] + b2;
        const float e = expf(-logA);              // one transcendental
        const float sg = 1.f/(1.f + e);
        const float gate = fminf(fmaxf(sg*1.2f - 0.1f, 0.f), 1.f);
        const float a = (c==0)?av.x:(c==1)?av.y:(c==2)?av.z:av.w;
        const float w = gate*a*a;
        wv[c] = w;
        rs[ii] += w;
        l0acc += 1.f/(1.f + 0.20543832f*e);       // sigma(logA + 1.58261088)
      }
      ushort4 bw;
      bw.x = f2bf(wv[0]); bw.y = f2bf(wv[1]); bw.z = f2bf(wv[2]); bw.w = f2bf(wv[3]);
      *(ushort4*)(bwrow + jl) = bw;
      outrow[jl+0] = wv[0]; outrow[jl+1] = wv[1];   // out+17: 4B-aligned only
      outrow[jl+2] = wv[2]; outrow[jl+3] = wv[3];
    }
  }

  #pragma unroll
  for (int m = 1; m < 16; m <<= 1) {
    rs[0] += __shfl_xor(rs[0], m, 16);
    rs[1] += __shfl_xor(rs[1], m, 16);
  }
  if (jslot == 0) {
    atomicAdd(&row_sum[b*Nn + ia], rs[0]);
    atomicAdd(&row_sum[b*Nn + ib], rs[1]);
  }
  #pragma unroll
  for (int m = 1; m < 64; m <<= 1) l0acc += __shfl_xor(l0acc, m, 64);
  if ((t & 63) == 0) atomicAdd(l0_sum, l0acc);
}

// ---------------------------------------------------------------------------
// K3: gemm_pool. h_tile = relu((wadj/rs)@nfc + bconv), attention-pool tile
// into gr. Double-buffered staging: one barrier per K-iter.
// R7: softmax via wave shuffles — 2 barriers instead of ~18 tree steps.
__global__ __launch_bounds__(256) void gemm_pool(
    const ushort* __restrict__ wadjb, const ushort* __restrict__ nfcpk,
    const float* __restrict__ row_sum, const float* __restrict__ masks,
    const float* __restrict__ bconv, float* __restrict__ gr)
{
  const int bb = blockIdx.z;
  const int m0 = blockIdx.y*64, n0 = blockIdx.x*64;
  const int t = threadIdx.x;
  const int lane = t & 63, l15 = lane & 15, quad = lane >> 4;
  const int wv = t >> 6, wr = wv & 1, wc = wv >> 1;

  __shared__ ushort As[2][259*8];            // granule (akq*65 + m)*8 (dbuf)
  __shared__ ushort Bs[2][256*8];            // granule (bkq*64 + n)*8 (dbuf)
  __shared__ float ptile[64*65];             // weighted h tile
  __shared__ float red[8];
  __shared__ float attn_s[64];

  const ushort* Ab = wadjb + (long)bb*262144;
  const ushort* Bb = nfcpk + (long)bb*131072;
  const int am = t >> 2, akq = t & 3;
  const int bn = t & 63, bkq = t >> 6;

  f32x4 acc[2][2];
  #pragma unroll
  for (int i = 0; i < 2; ++i)
    #pragma unroll
    for (int j = 0; j < 2; ++j) acc[i][j] = (f32x4){0.f,0.f,0.f,0.f};

  // stage k=0 into buf0, prefetch k=32
  uint4 ra = *(const uint4*)(Ab + (long)(m0+am)*512 + akq*8);
  uint4 rb = *(const uint4*)(Bb + ((long)bkq*256 + n0 + bn)*8);
  *(uint4*)(As[0] + (akq*65 + am)*8) = ra;
  *(uint4*)(Bs[0] + (bkq*64 + bn)*8) = rb;
  ra = *(const uint4*)(Ab + (long)(m0+am)*512 + 32 + akq*8);
  rb = *(const uint4*)(Bb + ((long)(4 + bkq)*256 + n0 + bn)*8);

  for (int k0 = 0; k0 < 512; k0 += 32) {
    const int pb = (k0 >> 5) & 1;
    __syncthreads();
    if (k0 + 32 < 512) {
      *(uint4*)(As[1-pb] + (akq*65 + am)*8) = ra;
      *(uint4*)(Bs[1-pb] + (bkq*64 + bn)*8) = rb;
      if (k0 + 64 < 512) {
        ra = *(const uint4*)(Ab + (long)(m0+am)*512 + (k0+64) + akq*8);
        rb = *(const uint4*)(Bb + ((long)(((k0+64) >> 3) + bkq)*256 + n0 + bn)*8);
      }
    }
    bf16x8 af[2], bfr[2];
    #pragma unroll
    for (int i = 0; i < 2; ++i)
      af[i] = *(const bf16x8*)(As[pb] + (quad*65 + wr*32 + i*16 + l15)*8);
    #pragma unroll
    for (int j = 0; j < 2; ++j)
      bfr[j] = *(const bf16x8*)(Bs[pb] + (quad*64 + wc*32 + j*16 + l15)*8);
    #pragma unroll
    for (int i = 0; i < 2; ++i)
      #pragma unroll
      for (int j = 0; j < 2; ++j)
        acc[i][j] = __builtin_amdgcn_mfma_f32_16x16x32_bf16(
            af[i], bfr[j], acc[i][j], 0, 0, 0);
  }
  __syncthreads();

  // attention softmax over this batch's masked degrees (block-redundant):
  // wave-level shuffle reductions, 2 barriers total.
  {
    const float mk0 = masks[bb*Nn + t], mk1 = masks[bb*Nn + t + 256];
    const float lv0 = (mk0 > 0.f) ? row_sum[bb*Nn + t] : -1e9f;
    const float lv1 = (mk1 > 0.f) ? row_sum[bb*Nn + t + 256] : -1e9f;
    float m = fmaxf(lv0, lv1);
    #pragma unroll
    for (int s = 1; s < 64; s <<= 1) m = fmaxf(m, __shfl_xor(m, s, 64));
    if (lane == 0) red[wv] = m;
    __syncthreads();
    const float mx = fmaxf(fmaxf(red[0], red[1]), fmaxf(red[2], red[3]));
    float sm = expf(lv0 - mx) + expf(lv1 - mx);
    #pragma unroll
    for (int s = 1; s < 64; s <<= 1) sm += __shfl_xor(sm, s, 64);
    if (lane == 0) red[4 + wv] = sm;
    __syncthreads();
    const float sinv = 1.f/(red[4] + red[5] + red[6] + red[7]);
    if (t < 64) {
      const int node = m0 + t;
      const float mm = masks[bb*Nn + node];
      const float lv = (mm > 0.f) ? row_sum[bb*Nn + node] : -1e9f;
      attn_s[t] = expf(lv - mx)*sinv;
    }
    __syncthreads();
  }

  // epilogue: h = relu(acc/rs + bias), weight by attn, stash in LDS
  #pragma unroll
  for (int i = 0; i < 2; ++i) {
    #pragma unroll
    for (int j = 0; j < 2; ++j) {
      const int lcol = wc*32 + j*16 + l15;
      const float bias = bconv[n0 + lcol];
      #pragma unroll
      for (int rr = 0; rr < 4; ++rr) {
        const int lrow = wr*32 + i*16 + quad*4 + rr;
        const int row = m0 + lrow;
        const float scl = 1.f/(row_sum[bb*Nn + row] + 1e-8f);
        const float hv = fmaxf(acc[i][j][rr]*scl + bias, 0.f);
        ptile[lrow*65 + lcol] = hv * attn_s[lrow];
      }
    }
  }
  __syncthreads();
  if (t < 64) {
    float s = 0.f;
    #pragma unroll 4
    for (int rr = 0; rr < 64; ++rr) s += ptile[rr*65 + t];
    atomicAdd(&gr[bb*Hh + n0 + t], s);
  }
}

// ---------------------------------------------------------------------------
// K4: classifier head + spectral norm + losses. Single block.
// R7: wave-parallel LN stats (32 lanes/batch), fused 1-pass spectral-norm
//     reduction (sigma needs only {Sum v^2, Sum v*W0, Sum v*W1} since
//     normalize() is scale-invariant), 16x16-group logits. 4 barriers.
__global__ __launch_bounds__(256) void classifier_kernel(
    const float* __restrict__ gr, const float* __restrict__ W1c,
    const float* __restrict__ b1c, const float* __restrict__ ln_g,
    const float* __restrict__ ln_b, const float* __restrict__ W2c,
    const float* __restrict__ b2c, const float* __restrict__ u_sn,
    const int* __restrict__ labels, const float* __restrict__ l0_sum,
    float* __restrict__ out)
{
  const int t = threadIdx.x;
  __shared__ float grs[2048];
  __shared__ float z[8][128];
  __shared__ float mu_s[8], ri_s[8];
  __shared__ float part[6];
  __shared__ float sinv_s;
  __shared__ float lg[16];

  for (int p = t; p < 2048; p += 256) grs[p] = gr[p];
  __syncthreads();

  // z = relu(gr @ W1c + b1c): 4 outputs/thread, coalesced W1c columns
  #pragma unroll
  for (int p = 0; p < 4; ++p) {
    const int idx = t + p*256;
    const int b = idx >> 7, o = idx & 127;
    float acc = b1c[o];
    #pragma unroll 4
    for (int d = 0; d < 256; ++d) acc += grs[b*256 + d]*W1c[d*128 + o];
    z[b][o] = fmaxf(acc, 0.f);
  }
  __syncthreads();

  // LN stats: 32 lanes per batch, two-pass (mean then var), shuffle reduce
  {
    const int b = t >> 5, g = t & 31;
    const float4 zv = *(const float4*)(&z[b][g*4]);
    float s1 = zv.x + zv.y + zv.z + zv.w;
    #pragma unroll
    for (int m = 1; m < 32; m <<= 1) s1 += __shfl_xor(s1, m, 32);
    const float mu = s1*(1.f/128.f);
    float s2 = (zv.x-mu)*(zv.x-mu) + (zv.y-mu)*(zv.y-mu)
             + (zv.z-mu)*(zv.z-mu) + (zv.w-mu)*(zv.w-mu);
    #pragma unroll
    for (int m = 1; m < 32; m <<= 1) s2 += __shfl_xor(s2, m, 32);
    if (g == 0) { mu_s[b] = mu; ri_s[b] = rsqrtf(s2*(1.f/128.f) + 1e-5f); }
  }

  // spectral norm: one fused 3-value reduction over the 128 rows of W2c
  if (t < 128) {
    const float w0 = W2c[2*t], w1 = W2c[2*t+1];
    const float vt = w0*u_sn[0] + w1*u_sn[1];
    float svv = vt*vt, sa = vt*w0, sb = vt*w1;
    #pragma unroll
    for (int m = 1; m < 64; m <<= 1) {
      svv += __shfl_xor(svv, m, 64);
      sa  += __shfl_xor(sa , m, 64);
      sb  += __shfl_xor(sb , m, 64);
    }
    if ((t & 63) == 0) {
      const int w = t >> 6;
      part[w*3+0] = svv; part[w*3+1] = sa; part[w*3+2] = sb;
    }
  }
  __syncthreads();                 // covers mu_s/ri_s + part[]
  if (t == 0) {
    const float svv = part[0] + part[3];
    const float sa  = part[1] + part[4];
    const float sb  = part[2] + part[5];
    const float vninv = 1.f/fmaxf(sqrtf(svv), 1e-12f);
    const float u20 = sa*vninv, u21 = sb*vninv;
    const float uninv = 1.f/fmaxf(sqrtf(u20*u20 + u21*u21), 1e-12f);
    const float u2n0 = u20*uninv, u2n1 = u21*uninv;
    const float sigma = vninv*(u2n0*sa + u2n1*sb);
    sinv_s = 1.f/sigma;
  }
  __syncthreads();

  // logits: 16 groups of 16 lanes, each group owns one (b,c)
  {
    const float sinv = sinv_s;
    const int grp = t >> 4, g = t & 15;
    const int b = grp >> 1, c = grp & 1;
    const float mu = mu_s[b], ri = ri_s[b];
    float acc = 0.f;
    #pragma unroll
    for (int j = 0; j < 8; ++j) {
      const int o = g*8 + j;
      const float zln = (z[b][o]-mu)*ri*ln_g[o] + ln_b[o];
      acc += zln*W2c[2*o + c];
    }
    #pragma unroll
    for (int m = 1; m < 16; m <<= 1) acc += __shfl_xor(acc, m, 16);
    if (g == 0) {
      const float lgv = acc*sinv + b2c[c];
      lg[grp] = lgv;
      out[grp] = lgv;
    }
  }
  __syncthreads();
  if (t == 0) {
    float closs = 0.f;
    #pragma unroll
    for (int b = 0; b < 8; ++b) {
      const float a0 = lg[2*b], a1 = lg[2*b+1];
      const float m = fmaxf(a0, a1);
      const float lse = m + logf(expf(a0-m) + expf(a1-m));
      closs += lse - lg[2*b + labels[b]];
    }
    out[16] = closs*(1.f/8.f) + 0.01f*l0_sum[0];
  }
}

extern "C" void kernel_launch(void* const* d_in, const int* in_sizes, int n_in,
                              void* d_out, int out_size, void* d_ws, size_t ws_size,
                              hipStream_t stream) {
  const float* node_feat = (const float*)d_in[0];
  const int*   labels    = (const int*)d_in[1];
  const float* adjs      = (const float*)d_in[2];
  const float* masks     = (const float*)d_in[3];
  const float* Wa        = (const float*)d_in[4];
  const float* Wb        = (const float*)d_in[5];
  const float* be        = (const float*)d_in[6];
  const float* W2e       = (const float*)d_in[7];
  const float* b2e       = (const float*)d_in[8];
  const float* Wconv     = (const float*)d_in[9];
  const float* bconv     = (const float*)d_in[10];
  const float* W1c       = (const float*)d_in[11];
  const float* b1c       = (const float*)d_in[12];
  const float* ln_g      = (const float*)d_in[13];
  const float* ln_b      = (const float*)d_in[14];
  const float* W2c       = (const float*)d_in[15];
  const float* b2c       = (const float*)d_in[16];
  const float* u_sn      = (const float*)d_in[17];

  float* out = (float*)d_out;
  float* ws  = (float*)d_ws;
  ushort* nfcpk  = (ushort*)(ws + WS_NFCPK);
  float*  e1     = ws + WS_E1;
  float*  e2     = ws + WS_E2;
  ushort* wadjb  = (ushort*)(ws + WS_WADJB);
  float*  row_sum= ws + WS_RS;
  float*  l0s    = ws + WS_L0;
  float*  gr     = ws + WS_GR;
  ushort* wabpk  = (ushort*)(ws + WS_WABPK);
  ushort* wcpk   = (ushort*)(ws + WS_WCPK);

  pack_weights<<<80, 256, 0, stream>>>(Wconv, Wa, Wb, wcpk, wabpk);
  norm_e12_nfc<<<256, 256, 0, stream>>>(node_feat, wabpk, wcpk, be, nfcpk,
                                        e1, e2, row_sum, gr, l0s);
  edge_kernel<<<dim3(Nn/128, Nn/32, Bsz), 256, 0, stream>>>(
      e1, e2, W2e, b2e, adjs, out + 17, wadjb, row_sum, l0s);
  gemm_pool<<<dim3(Hh/64, Nn/64, Bsz), 256, 0, stream>>>(
      wadjb, nfcpk, row_sum, masks, bconv, gr);
  classifier_kernel<<<1, 256, 0, stream>>>(gr, W1c, b1c, ln_g, ln_b, W2c, b2c,
                                           u_sn, labels, l0s, out);
}

// Round 2
// 174.893 us; speedup vs baseline: 1.2161x; 1.2161x over previous
//
#include <hip/hip_runtime.h>

// ---------------------------------------------------------------------------
// ImprovedEdgeGNN forward — MI355X
// Sizes: B=8, N=512, D=512, H=256, E=32, C=2
// out layout: [0:16) logits [8,2], [16] total_loss, [17:17+8*512*512) wadj
// R8: classifier z-GEMM was the R7 regression (57.5us/dispatch, top-5;
//     VGPR=24 -> ~4 loads in flight -> W1c read as serial HBM chain).
//     Fix: register-preload W1c (32x dwordx4/thread, all independent ->
//     full MLP), 8-batch reuse per element, LDS cross-dgroup reduce.
//     Everything else unchanged from R7.
//     Decision rule: if classifier <=8us and dur >=195 with fills on top
//     at ~75-78% HBM, declare roofline next round.
// ---------------------------------------------------------------------------

#define Bsz 8
#define Nn  512
#define Dd  512
#define Hh  256
#define Ee  32

// ws offsets (floats)
#define WS_NFCPK  0L          // nfc bf16 k-packed [8][64oct][256c][8] = 524,288 f
#define WS_E1     524288L     // [4096][32] f32 (be folded)            131,072 f
#define WS_E2     655360L     // [4096][32] f32                        131,072 f
#define WS_WADJB  786432L     // wadj bf16 [8][512][512]             1,048,576 f
#define WS_RS     1835008L    // [4096] raw row sums (= imp)
#define WS_L0     1839104L    // [8]
#define WS_GR     1839112L    // [8][256]
#define WS_WABPK  1841160L    // [Wa|Wb] bf16 pk [64kq][64n][8]         16,384 f
#define WS_WCPK   1857544L    // Wconv bf16 pk [64kq][256n][8]          65,536 f

typedef __bf16 bf16x8 __attribute__((ext_vector_type(8)));
typedef float  f32x4  __attribute__((ext_vector_type(4)));

__device__ inline ushort f2bf(float f) {
  union { float f; unsigned u; } c; c.f = f;
  return (ushort)((c.u + 0x7fffu + ((c.u >> 16) & 1u)) >> 16);
}

// ---------------------------------------------------------------------------
// K0: pack weights to bf16 k-packed granules [(K/8)][N][8].
__global__ __launch_bounds__(256) void pack_weights(
    const float* __restrict__ Wconv, const float* __restrict__ Wa,
    const float* __restrict__ Wb, ushort* __restrict__ wcpk,
    ushort* __restrict__ wabpk)
{
  const int g = blockIdx.x*256 + threadIdx.x;
  if (g < 16384) {                       // Wconv granules
    const int kq = g >> 8, n = g & 255;
    ushort tmp[8];
    #pragma unroll
    for (int j = 0; j < 8; ++j) tmp[j] = f2bf(Wconv[(kq*8 + j)*Hh + n]);
    *(uint4*)(wcpk + (long)g*8) = *(uint4*)tmp;
  } else if (g < 16384 + 4096) {         // Wa|Wb granules
    const int gg = g - 16384;
    const int kq = gg >> 6, n = gg & 63;
    const float* W = (n < 32) ? Wa : Wb;
    const int e = n & 31;
    ushort tmp[8];
    #pragma unroll
    for (int j = 0; j < 8; ++j) tmp[j] = f2bf(W[(kq*8 + j)*Ee + e]);
    *(uint4*)(wabpk + (long)gg*8) = *(uint4*)tmp;
  }
}

// ---------------------------------------------------------------------------
// K1: fused normalize + e1|e2 + nfc = nf@Wconv. 256 blocks x 16 rows.
// Double-buffered B staging: one barrier per K-iter.
__global__ __launch_bounds__(256) void norm_e12_nfc(
    const float* __restrict__ nfeat, const ushort* __restrict__ wabpk,
    const ushort* __restrict__ wcpk, const float* __restrict__ be,
    ushort* __restrict__ nfcpk, float* __restrict__ e1, float* __restrict__ e2,
    float* __restrict__ row_sum, float* __restrict__ gr,
    float* __restrict__ l0_sum)
{
  const int blk = blockIdx.x;
  const int r0 = blk*16;               // global row base (b*512 + local)
  const int b = r0 >> 9;
  const int t = threadIdx.x;
  const int r = t >> 4;                // local row 0..15
  const int seg = t & 15;              // 32-col segment

  __shared__ ushort As[(63*17 + 15 + 1)*8];   // granule (kq*17 + row)*8
  __shared__ ushort BsA[2][4*64*8];           // Wa|Wb tile granules (dbuf)
  __shared__ ushort BsC[2][4*256*8];          // Wconv tile granules (dbuf)

  // ---- phase 1: load 32 f32/thread, row norm, bf16 granules to LDS ----
  float4 v[8];
  const float* src = nfeat + (long)(r0 + r)*Dd + seg*32;
  #pragma unroll
  for (int i = 0; i < 8; ++i) v[i] = *(const float4*)(src + i*4);
  float s = 0.f;
  #pragma unroll
  for (int i = 0; i < 8; ++i)
    s += v[i].x*v[i].x + v[i].y*v[i].y + v[i].z*v[i].z + v[i].w*v[i].w;
  #pragma unroll
  for (int m = 1; m < 16; m <<= 1) s += __shfl_xor(s, m, 16);
  const float sc = 1.f / fmaxf(sqrtf(s), 1e-12f);
  #pragma unroll
  for (int q = 0; q < 4; ++q) {
    ushort tmp[8];
    const float4 a = v[2*q], bq = v[2*q+1];
    tmp[0]=f2bf(a.x*sc);  tmp[1]=f2bf(a.y*sc);  tmp[2]=f2bf(a.z*sc);  tmp[3]=f2bf(a.w*sc);
    tmp[4]=f2bf(bq.x*sc); tmp[5]=f2bf(bq.y*sc); tmp[6]=f2bf(bq.z*sc); tmp[7]=f2bf(bq.w*sc);
    *(uint4*)(As + ((seg*4 + q)*17 + r)*8) = *(uint4*)tmp;
  }
  if (t < 16) row_sum[r0 + t] = 0.f;
  if (blk == 0) {
    for (int p = t; p < Bsz*Hh; p += 256) gr[p] = 0.f;
    if (t == 0) *l0_sum = 0.f;
  }

  // ---- phase 2: MFMA over K, double-buffered weight staging ----
  const int lane = t & 63, l15 = lane & 15, quad = lane >> 4;
  const int w = t >> 6;                  // wave id 0..3
  const int abq = t >> 6, abn = t & 63;  // Wa|Wb staging map

  f32x4 acc_e = {0.f, 0.f, 0.f, 0.f};
  f32x4 acc_c[4];
  #pragma unroll
  for (int j = 0; j < 4; ++j) acc_c[j] = (f32x4){0.f,0.f,0.f,0.f};

  // stage k=0 into buf 0, then prefetch k=32 into regs
  uint4 pab = *(const uint4*)(wabpk + ((long)abq*64 + abn)*8);
  uint4 pc[4];
  #pragma unroll
  for (int p = 0; p < 4; ++p) {
    const int g = t + p*256;
    pc[p] = *(const uint4*)(wcpk + ((long)(g >> 8)*256 + (g & 255))*8);
  }
  *(uint4*)(BsA[0] + (abq*64 + abn)*8) = pab;
  #pragma unroll
  for (int p = 0; p < 4; ++p) {
    const int g = t + p*256;
    *(uint4*)(BsC[0] + ((g >> 8)*256 + (g & 255))*8) = pc[p];
  }
  {
    pab = *(const uint4*)(wabpk + ((long)(4 + abq)*64 + abn)*8);
    #pragma unroll
    for (int p = 0; p < 4; ++p) {
      const int g = t + p*256;
      pc[p] = *(const uint4*)(wcpk + ((long)(4 + (g >> 8))*256 + (g & 255))*8);
    }
  }

  for (int k0 = 0; k0 < 512; k0 += 32) {
    const int pb = (k0 >> 5) & 1;
    __syncthreads();                     // buf[pb] writes visible; old reads done
    if (k0 + 32 < 512) {
      // stage k0+32 into buf[1-pb] (regs hold it), then prefetch k0+64
      *(uint4*)(BsA[1-pb] + (abq*64 + abn)*8) = pab;
      #pragma unroll
      for (int p = 0; p < 4; ++p) {
        const int g = t + p*256;
        *(uint4*)(BsC[1-pb] + ((g >> 8)*256 + (g & 255))*8) = pc[p];
      }
      if (k0 + 64 < 512) {
        const int kb = (k0 + 64) >> 3;
        pab = *(const uint4*)(wabpk + ((long)(kb + abq)*64 + abn)*8);
        #pragma unroll
        for (int p = 0; p < 4; ++p) {
          const int g = t + p*256;
          pc[p] = *(const uint4*)(wcpk + ((long)(kb + (g >> 8))*256 + (g & 255))*8);
        }
      }
    }
    const bf16x8 af = *(const bf16x8*)(As + (((k0 >> 3) + quad)*17 + l15)*8);
    const bf16x8 bfa = *(const bf16x8*)(BsA[pb] + (quad*64 + w*16 + l15)*8);
    acc_e = __builtin_amdgcn_mfma_f32_16x16x32_bf16(af, bfa, acc_e, 0, 0, 0);
    #pragma unroll
    for (int fn = 0; fn < 4; ++fn) {
      const bf16x8 bfc = *(const bf16x8*)(BsC[pb] + (quad*256 + w*64 + fn*16 + l15)*8);
      acc_c[fn] = __builtin_amdgcn_mfma_f32_16x16x32_bf16(af, bfc, acc_c[fn], 0, 0, 0);
    }
  }

  // ---- epilogue A: e1|e2 (wave w -> cols w*16..+15) ----
  {
    const int col = w*16 + l15;
    #pragma unroll
    for (int rr = 0; rr < 4; ++rr) {
      const int row = r0 + quad*4 + rr;
      if (col < 32) e1[(long)row*Ee + col] = acc_e[rr] + be[col];
      else          e2[(long)row*Ee + (col - 32)] = acc_e[rr];
    }
  }

  // ---- epilogue B: nfc -> k-packed global via LDS transpose ----
  __syncthreads();                       // all frag reads of BsC done
  ushort* tile = BsC[0];                 // [16][260] bf16
  #pragma unroll
  for (int fn = 0; fn < 4; ++fn) {
    const int col = w*64 + fn*16 + l15;
    #pragma unroll
    for (int rr = 0; rr < 4; ++rr)
      tile[(quad*4 + rr)*260 + col] = f2bf(acc_c[fn][rr]);
  }
  __syncthreads();
  #pragma unroll
  for (int p = 0; p < 2; ++p) {
    const int g = t + p*256;
    const int oct = g >> 8, c = g & 255;
    ushort tmp[8];
    #pragma unroll
    for (int j = 0; j < 8; ++j) tmp[j] = tile[(oct*8 + j)*260 + c];
    const long og = ((r0 & 511) >> 3) + oct;     // node-octet within batch
    *(uint4*)(nfcpk + ((long)b*16384 + og*256 + c)*8) = *(uint4*)tmp;
  }
}

// ---------------------------------------------------------------------------
// K2: tiled edge scoring. Block = (b, 32-row i-tile, 128-col j-tile).
// Single expf per edge — sigma(logA) = 1/(1+e), sigma(logA+C) = 1/(1+K*e)
// with e = expf(-logA), K = exp(-1.58261088) = 0.20543832.
__global__ __launch_bounds__(256) void edge_kernel(
    const float* __restrict__ e1, const float* __restrict__ e2,
    const float* __restrict__ W2e, const float* __restrict__ b2e,
    const float* __restrict__ adjs, float* __restrict__ out_wadj,
    ushort* __restrict__ wadj_b, float* __restrict__ row_sum,
    float* __restrict__ l0_sum)
{
  const int b  = blockIdx.z;
  const int i0 = blockIdx.y * 32;
  const int j0 = blockIdx.x * 128;
  const int t  = threadIdx.x;

  __shared__ float e2s[32*132];

  #pragma unroll
  for (int itr = 0; itr < 4; ++itr) {
    const int idx = t + itr*256;
    const int kq = idx & 7, jg = idx >> 3;
    const float4 v = *(const float4*)(e2 + ((long)(b*Nn + j0 + jg))*Ee + kq*4);
    e2s[(kq*4+0)*132 + jg] = v.x;
    e2s[(kq*4+1)*132 + jg] = v.y;
    e2s[(kq*4+2)*132 + jg] = v.z;
    e2s[(kq*4+3)*132 + jg] = v.w;
  }

  const int pair  = t >> 4;
  const int jslot = t & 15;
  const int ia = i0 + pair*2;
  const int ib = ia + 1;
  const int ja = jslot*4;
  const int jb = ja + 64;

  float e1af[32], e1bf[32], w2f[32];
  #pragma unroll
  for (int q = 0; q < 8; ++q) {
    *(float4*)(&e1af[q*4]) = *(const float4*)(e1 + ((long)(b*Nn + ia))*Ee + q*4);
    *(float4*)(&e1bf[q*4]) = *(const float4*)(e1 + ((long)(b*Nn + ib))*Ee + q*4);
    *(float4*)(&w2f[q*4])  = *(const float4*)(W2e + q*4);
  }
  const float b2 = b2e[0];
  __syncthreads();

  float acc[2][8] = {};
  #pragma unroll
  for (int k = 0; k < 32; ++k) {
    const float4 va = *(const float4*)(e2s + k*132 + ja);
    const float4 vb = *(const float4*)(e2s + k*132 + jb);
    const float w = w2f[k];
    const float ea = e1af[k], eb = e1bf[k];
    acc[0][0] += fmaxf(ea+va.x, 0.f)*w;
    acc[0][1] += fmaxf(ea+va.y, 0.f)*w;
    acc[0][2] += fmaxf(ea+va.z, 0.f)*w;
    acc[0][3] += fmaxf(ea+va.w, 0.f)*w;
    acc[0][4] += fmaxf(ea+vb.x, 0.f)*w;
    acc[0][5] += fmaxf(ea+vb.y, 0.f)*w;
    acc[0][6] += fmaxf(ea+vb.z, 0.f)*w;
    acc[0][7] += fmaxf(ea+vb.w, 0.f)*w;
    acc[1][0] += fmaxf(eb+va.x, 0.f)*w;
    acc[1][1] += fmaxf(eb+va.y, 0.f)*w;
    acc[1][2] += fmaxf(eb+va.z, 0.f)*w;
    acc[1][3] += fmaxf(eb+va.w, 0.f)*w;
    acc[1][4] += fmaxf(eb+vb.x, 0.f)*w;
    acc[1][5] += fmaxf(eb+vb.y, 0.f)*w;
    acc[1][6] += fmaxf(eb+vb.z, 0.f)*w;
    acc[1][7] += fmaxf(eb+vb.w, 0.f)*w;
  }

  float rs[2] = {0.f, 0.f};
  float l0acc = 0.f;
  #pragma unroll
  for (int ii = 0; ii < 2; ++ii) {
    const int i = (ii == 0) ? ia : ib;
    const float* arow = adjs     + ((long)(b*Nn + i))*Nn + j0;
    ushort* bwrow     = wadj_b   + ((long)(b*Nn + i))*Nn + j0;
    float* outrow     = out_wadj + ((long)(b*Nn + i))*Nn + j0;
    #pragma unroll
    for (int h2 = 0; h2 < 2; ++h2) {
      const int jl = (h2 == 0) ? ja : jb;
      const float4 av = *(const float4*)(arow + jl);
      float wv[4];
      #pragma unroll
      for (int c = 0; c < 4; ++c) {
        const float logA = acc[ii][h2*4 + c] + b2;
        const float e = expf(-logA);              // one transcendental
        const float sg = 1.f/(1.f + e);
        const float gate = fminf(fmaxf(sg*1.2f - 0.1f, 0.f), 1.f);
        const float a = (c==0)?av.x:(c==1)?av.y:(c==2)?av.z:av.w;
        const float w = gate*a*a;
        wv[c] = w;
        rs[ii] += w;
        l0acc += 1.f/(1.f + 0.20543832f*e);       // sigma(logA + 1.58261088)
      }
      ushort4 bw;
      bw.x = f2bf(wv[0]); bw.y = f2bf(wv[1]); bw.z = f2bf(wv[2]); bw.w = f2bf(wv[3]);
      *(ushort4*)(bwrow + jl) = bw;
      outrow[jl+0] = wv[0]; outrow[jl+1] = wv[1];   // out+17: 4B-aligned only
      outrow[jl+2] = wv[2]; outrow[jl+3] = wv[3];
    }
  }

  #pragma unroll
  for (int m = 1; m < 16; m <<= 1) {
    rs[0] += __shfl_xor(rs[0], m, 16);
    rs[1] += __shfl_xor(rs[1], m, 16);
  }
  if (jslot == 0) {
    atomicAdd(&row_sum[b*Nn + ia], rs[0]);
    atomicAdd(&row_sum[b*Nn + ib], rs[1]);
  }
  #pragma unroll
  for (int m = 1; m < 64; m <<= 1) l0acc += __shfl_xor(l0acc, m, 64);
  if ((t & 63) == 0) atomicAdd(l0_sum, l0acc);
}

// ---------------------------------------------------------------------------
// K3: gemm_pool. h_tile = relu((wadj/rs)@nfc + bconv), attention-pool tile
// into gr. Double-buffered staging: one barrier per K-iter.
// Softmax via wave shuffles — 2 barriers.
__global__ __launch_bounds__(256) void gemm_pool(
    const ushort* __restrict__ wadjb, const ushort* __restrict__ nfcpk,
    const float* __restrict__ row_sum, const float* __restrict__ masks,
    const float* __restrict__ bconv, float* __restrict__ gr)
{
  const int bb = blockIdx.z;
  const int m0 = blockIdx.y*64, n0 = blockIdx.x*64;
  const int t = threadIdx.x;
  const int lane = t & 63, l15 = lane & 15, quad = lane >> 4;
  const int wv = t >> 6, wr = wv & 1, wc = wv >> 1;

  __shared__ ushort As[2][259*8];            // granule (akq*65 + m)*8 (dbuf)
  __shared__ ushort Bs[2][256*8];            // granule (bkq*64 + n)*8 (dbuf)
  __shared__ float ptile[64*65];             // weighted h tile
  __shared__ float red[8];
  __shared__ float attn_s[64];

  const ushort* Ab = wadjb + (long)bb*262144;
  const ushort* Bb = nfcpk + (long)bb*131072;
  const int am = t >> 2, akq = t & 3;
  const int bn = t & 63, bkq = t >> 6;

  f32x4 acc[2][2];
  #pragma unroll
  for (int i = 0; i < 2; ++i)
    #pragma unroll
    for (int j = 0; j < 2; ++j) acc[i][j] = (f32x4){0.f,0.f,0.f,0.f};

  // stage k=0 into buf0, prefetch k=32
  uint4 ra = *(const uint4*)(Ab + (long)(m0+am)*512 + akq*8);
  uint4 rb = *(const uint4*)(Bb + ((long)bkq*256 + n0 + bn)*8);
  *(uint4*)(As[0] + (akq*65 + am)*8) = ra;
  *(uint4*)(Bs[0] + (bkq*64 + bn)*8) = rb;
  ra = *(const uint4*)(Ab + (long)(m0+am)*512 + 32 + akq*8);
  rb = *(const uint4*)(Bb + ((long)(4 + bkq)*256 + n0 + bn)*8);

  for (int k0 = 0; k0 < 512; k0 += 32) {
    const int pb = (k0 >> 5) & 1;
    __syncthreads();
    if (k0 + 32 < 512) {
      *(uint4*)(As[1-pb] + (akq*65 + am)*8) = ra;
      *(uint4*)(Bs[1-pb] + (bkq*64 + bn)*8) = rb;
      if (k0 + 64 < 512) {
        ra = *(const uint4*)(Ab + (long)(m0+am)*512 + (k0+64) + akq*8);
        rb = *(const uint4*)(Bb + ((long)(((k0+64) >> 3) + bkq)*256 + n0 + bn)*8);
      }
    }
    bf16x8 af[2], bfr[2];
    #pragma unroll
    for (int i = 0; i < 2; ++i)
      af[i] = *(const bf16x8*)(As[pb] + (quad*65 + wr*32 + i*16 + l15)*8);
    #pragma unroll
    for (int j = 0; j < 2; ++j)
      bfr[j] = *(const bf16x8*)(Bs[pb] + (quad*64 + wc*32 + j*16 + l15)*8);
    #pragma unroll
    for (int i = 0; i < 2; ++i)
      #pragma unroll
      for (int j = 0; j < 2; ++j)
        acc[i][j] = __builtin_amdgcn_mfma_f32_16x16x32_bf16(
            af[i], bfr[j], acc[i][j], 0, 0, 0);
  }
  __syncthreads();

  // attention softmax over this batch's masked degrees (block-redundant):
  // wave-level shuffle reductions, 2 barriers total.
  {
    const float mk0 = masks[bb*Nn + t], mk1 = masks[bb*Nn + t + 256];
    const float lv0 = (mk0 > 0.f) ? row_sum[bb*Nn + t] : -1e9f;
    const float lv1 = (mk1 > 0.f) ? row_sum[bb*Nn + t + 256] : -1e9f;
    float m = fmaxf(lv0, lv1);
    #pragma unroll
    for (int s = 1; s < 64; s <<= 1) m = fmaxf(m, __shfl_xor(m, s, 64));
    if (lane == 0) red[wv] = m;
    __syncthreads();
    const float mx = fmaxf(fmaxf(red[0], red[1]), fmaxf(red[2], red[3]));
    float sm = expf(lv0 - mx) + expf(lv1 - mx);
    #pragma unroll
    for (int s = 1; s < 64; s <<= 1) sm += __shfl_xor(sm, s, 64);
    if (lane == 0) red[4 + wv] = sm;
    __syncthreads();
    const float sinv = 1.f/(red[4] + red[5] + red[6] + red[7]);
    if (t < 64) {
      const int node = m0 + t;
      const float mm = masks[bb*Nn + node];
      const float lv = (mm > 0.f) ? row_sum[bb*Nn + node] : -1e9f;
      attn_s[t] = expf(lv - mx)*sinv;
    }
    __syncthreads();
  }

  // epilogue: h = relu(acc/rs + bias), weight by attn, stash in LDS
  #pragma unroll
  for (int i = 0; i < 2; ++i) {
    #pragma unroll
    for (int j = 0; j < 2; ++j) {
      const int lcol = wc*32 + j*16 + l15;
      const float bias = bconv[n0 + lcol];
      #pragma unroll
      for (int rr = 0; rr < 4; ++rr) {
        const int lrow = wr*32 + i*16 + quad*4 + rr;
        const int row = m0 + lrow;
        const float scl = 1.f/(row_sum[bb*Nn + row] + 1e-8f);
        const float hv = fmaxf(acc[i][j][rr]*scl + bias, 0.f);
        ptile[lrow*65 + lcol] = hv * attn_s[lrow];
      }
    }
  }
  __syncthreads();
  if (t < 64) {
    float s = 0.f;
    #pragma unroll 4
    for (int rr = 0; rr < 64; ++rr) s += ptile[rr*65 + t];
    atomicAdd(&gr[bb*Hh + n0 + t], s);
  }
}

// ---------------------------------------------------------------------------
// K4: classifier head + spectral norm + losses. Single block.
// R8: z-GEMM via register-preloaded W1c. Thread (og=t&31, dr=t>>5) loads
//     W1c[dr*32..+32)[og*4..+4) as 32 independent dwordx4 (full MLP, one
//     HBM round-trip for all 128KB), computes partials for all 8 batches
//     from registers, then LDS-reduces across the 8 d-groups.
__global__ __launch_bounds__(256) void classifier_kernel(
    const float* __restrict__ gr, const float* __restrict__ W1c,
    const float* __restrict__ b1c, const float* __restrict__ ln_g,
    const float* __restrict__ ln_b, const float* __restrict__ W2c,
    const float* __restrict__ b2c, const float* __restrict__ u_sn,
    const int* __restrict__ labels, const float* __restrict__ l0_sum,
    float* __restrict__ out)
{
  const int t = threadIdx.x;
  const int og = t & 31;               // output col group (4 cols)
  const int dr = t >> 5;               // d-group (32 d's)

  __shared__ float grs[2048];
  __shared__ float part[8][8][128];    // [dgroup][batch][col] 32 KB
  __shared__ float z[8][128];
  __shared__ float mu_s[8], ri_s[8];
  __shared__ float snpart[6];
  __shared__ float sinv_s;
  __shared__ float lg[16];

  // ---- issue all W1c loads up front: 32 independent dwordx4 per thread ----
  float4 w[32];
  const float* wp = W1c + (long)dr*32*128 + og*4;
  #pragma unroll
  for (int i = 0; i < 32; ++i) w[i] = *(const float4*)(wp + i*128);

  // gr -> LDS (overlaps with W1c loads in flight)
  #pragma unroll
  for (int p = 0; p < 8; ++p) grs[t + p*256] = gr[t + p*256];
  __syncthreads();

  // ---- partial z: all 8 batches reuse each W1c element ----
  float4 acc[8];
  #pragma unroll
  for (int b = 0; b < 8; ++b) acc[b] = (float4){0.f,0.f,0.f,0.f};
  #pragma unroll
  for (int i = 0; i < 32; ++i) {
    const int d = dr*32 + i;
    #pragma unroll
    for (int b = 0; b < 8; ++b) {
      const float g = grs[b*256 + d];
      acc[b].x += g*w[i].x; acc[b].y += g*w[i].y;
      acc[b].z += g*w[i].z; acc[b].w += g*w[i].w;
    }
  }
  #pragma unroll
  for (int b = 0; b < 8; ++b)
    *(float4*)(&part[dr][b][og*4]) = acc[b];
  __syncthreads();

  // ---- reduce d-groups, bias, relu -> z ----
  #pragma unroll
  for (int p = 0; p < 4; ++p) {
    const int idx = t + p*256;
    const int b = idx >> 7, o = idx & 127;
    float s = b1c[o];
    #pragma unroll
    for (int d2 = 0; d2 < 8; ++d2) s += part[d2][b][o];
    z[b][o] = fmaxf(s, 0.f);
  }
  __syncthreads();

  // LN stats: 32 lanes per batch, shuffle reduce
  {
    const int b = t >> 5, g = t & 31;
    const float4 zv = *(const float4*)(&z[b][g*4]);
    float s1 = zv.x + zv.y + zv.z + zv.w;
    #pragma unroll
    for (int m = 1; m < 32; m <<= 1) s1 += __shfl_xor(s1, m, 32);
    const float mu = s1*(1.f/128.f);
    float s2 = (zv.x-mu)*(zv.x-mu) + (zv.y-mu)*(zv.y-mu)
             + (zv.z-mu)*(zv.z-mu) + (zv.w-mu)*(zv.w-mu);
    #pragma unroll
    for (int m = 1; m < 32; m <<= 1) s2 += __shfl_xor(s2, m, 32);
    if (g == 0) { mu_s[b] = mu; ri_s[b] = rsqrtf(s2*(1.f/128.f) + 1e-5f); }
  }

  // spectral norm: one fused 3-value reduction over the 128 rows of W2c
  if (t < 128) {
    const float w0 = W2c[2*t], w1 = W2c[2*t+1];
    const float vt = w0*u_sn[0] + w1*u_sn[1];
    float svv = vt*vt, sa = vt*w0, sb = vt*w1;
    #pragma unroll
    for (int m = 1; m < 64; m <<= 1) {
      svv += __shfl_xor(svv, m, 64);
      sa  += __shfl_xor(sa , m, 64);
      sb  += __shfl_xor(sb , m, 64);
    }
    if ((t & 63) == 0) {
      const int wd = t >> 6;
      snpart[wd*3+0] = svv; snpart[wd*3+1] = sa; snpart[wd*3+2] = sb;
    }
  }
  __syncthreads();                 // covers mu_s/ri_s + snpart[]
  if (t == 0) {
    const float svv = snpart[0] + snpart[3];
    const float sa  = snpart[1] + snpart[4];
    const float sb  = snpart[2] + snpart[5];
    const float vninv = 1.f/fmaxf(sqrtf(svv), 1e-12f);
    const float u20 = sa*vninv, u21 = sb*vninv;
    const float uninv = 1.f/fmaxf(sqrtf(u20*u20 + u21*u21), 1e-12f);
    const float u2n0 = u20*uninv, u2n1 = u21*uninv;
    const float sigma = vninv*(u2n0*sa + u2n1*sb);
    sinv_s = 1.f/sigma;
  }
  __syncthreads();

  // logits: 16 groups of 16 lanes, each group owns one (b,c)
  {
    const float sinv = sinv_s;
    const int grp = t >> 4, g = t & 15;
    const int b = grp >> 1, c = grp & 1;
    const float mu = mu_s[b], ri = ri_s[b];
    float acc2 = 0.f;
    #pragma unroll
    for (int j = 0; j < 8; ++j) {
      const int o = g*8 + j;
      const float zln = (z[b][o]-mu)*ri*ln_g[o] + ln_b[o];
      acc2 += zln*W2c[2*o + c];
    }
    #pragma unroll
    for (int m = 1; m < 16; m <<= 1) acc2 += __shfl_xor(acc2, m, 16);
    if (g == 0) {
      const float lgv = acc2*sinv + b2c[c];
      lg[grp] = lgv;
      out[grp] = lgv;
    }
  }
  __syncthreads();
  if (t == 0) {
    float closs = 0.f;
    #pragma unroll
    for (int b = 0; b < 8; ++b) {
      const float a0 = lg[2*b], a1 = lg[2*b+1];
      const float m = fmaxf(a0, a1);
      const float lse = m + logf(expf(a0-m) + expf(a1-m));
      closs += lse - lg[2*b + labels[b]];
    }
    out[16] = closs*(1.f/8.f) + 0.01f*l0_sum[0];
  }
}

extern "C" void kernel_launch(void* const* d_in, const int* in_sizes, int n_in,
                              void* d_out, int out_size, void* d_ws, size_t ws_size,
                              hipStream_t stream) {
  const float* node_feat = (const float*)d_in[0];
  const int*   labels    = (const int*)d_in[1];
  const float* adjs      = (const float*)d_in[2];
  const float* masks     = (const float*)d_in[3];
  const float* Wa        = (const float*)d_in[4];
  const float* Wb        = (const float*)d_in[5];
  const float* be        = (const float*)d_in[6];
  const float* W2e       = (const float*)d_in[7];
  const float* b2e       = (const float*)d_in[8];
  const float* Wconv     = (const float*)d_in[9];
  const float* bconv     = (const float*)d_in[10];
  const float* W1c       = (const float*)d_in[11];
  const float* b1c       = (const float*)d_in[12];
  const float* ln_g      = (const float*)d_in[13];
  const float* ln_b      = (const float*)d_in[14];
  const float* W2c       = (const float*)d_in[15];
  const float* b2c       = (const float*)d_in[16];
  const float* u_sn      = (const float*)d_in[17];

  float* out = (float*)d_out;
  float* ws  = (float*)d_ws;
  ushort* nfcpk  = (ushort*)(ws + WS_NFCPK);
  float*  e1     = ws + WS_E1;
  float*  e2     = ws + WS_E2;
  ushort* wadjb  = (ushort*)(ws + WS_WADJB);
  float*  row_sum= ws + WS_RS;
  float*  l0s    = ws + WS_L0;
  float*  gr     = ws + WS_GR;
  ushort* wabpk  = (ushort*)(ws + WS_WABPK);
  ushort* wcpk   = (ushort*)(ws + WS_WCPK);

  pack_weights<<<80, 256, 0, stream>>>(Wconv, Wa, Wb, wcpk, wabpk);
  norm_e12_nfc<<<256, 256, 0, stream>>>(node_feat, wabpk, wcpk, be, nfcpk,
                                        e1, e2, row_sum, gr, l0s);
  edge_kernel<<<dim3(Nn/128, Nn/32, Bsz), 256, 0, stream>>>(
      e1, e2, W2e, b2e, adjs, out + 17, wadjb, row_sum, l0s);
  gemm_pool<<<dim3(Hh/64, Nn/64, Bsz), 256, 0, stream>>>(
      wadjb, nfcpk, row_sum, masks, bconv, gr);
  classifier_kernel<<<1, 256, 0, stream>>>(gr, W1c, b1c, ln_g, ln_b, W2c, b2c,
                                           u_sn, labels, l0s, out);
}

// Round 3
// 164.953 us; speedup vs baseline: 1.2894x; 1.0603x over previous
//
#include <hip/hip_runtime.h>

// ---------------------------------------------------------------------------
// ImprovedEdgeGNN forward — MI355X
// Sizes: B=8, N=512, D=512, H=256, E=32, C=2
// out layout: [0:16) logits [8,2], [16] total_loss, [17:17+8*512*512) wadj
// R9: edge_kernel was latency-bound (56us, VALU 13%, HBM 4%, occ 16%,
//     grid 512 = 2 blocks/CU). Retile 32x128 -> 16x64 (2048 blocks,
//     8/CU), early adjs load, l0 via per-block partials (no same-address
//     atomics; classifier reduces the 2048 partials).
//     Prediction: edge 56 -> 12-18us, occ >= 40%, dur 175 -> ~135.
// ---------------------------------------------------------------------------

#define Bsz 8
#define Nn  512
#define Dd  512
#define Hh  256
#define Ee  32

// ws offsets (floats)
#define WS_NFCPK  0L          // nfc bf16 k-packed [8][64oct][256c][8] = 524,288 f
#define WS_E1     524288L     // [4096][32] f32 (be folded)            131,072 f
#define WS_E2     655360L     // [4096][32] f32                        131,072 f
#define WS_WADJB  786432L     // wadj bf16 [8][512][512]             1,048,576 f
#define WS_RS     1835008L    // [4096] raw row sums (= imp)
#define WS_L0     1839104L    // [8] (unused since R9)
#define WS_GR     1839112L    // [8][256]
#define WS_WABPK  1841160L    // [Wa|Wb] bf16 pk [64kq][64n][8]         16,384 f
#define WS_WCPK   1857544L    // Wconv bf16 pk [64kq][256n][8]          65,536 f
#define WS_L0P    1923080L    // [2048] per-block l0 partials

typedef __bf16 bf16x8 __attribute__((ext_vector_type(8)));
typedef float  f32x4  __attribute__((ext_vector_type(4)));

__device__ inline ushort f2bf(float f) {
  union { float f; unsigned u; } c; c.f = f;
  return (ushort)((c.u + 0x7fffu + ((c.u >> 16) & 1u)) >> 16);
}

// ---------------------------------------------------------------------------
// K0: pack weights to bf16 k-packed granules [(K/8)][N][8].
__global__ __launch_bounds__(256) void pack_weights(
    const float* __restrict__ Wconv, const float* __restrict__ Wa,
    const float* __restrict__ Wb, ushort* __restrict__ wcpk,
    ushort* __restrict__ wabpk)
{
  const int g = blockIdx.x*256 + threadIdx.x;
  if (g < 16384) {                       // Wconv granules
    const int kq = g >> 8, n = g & 255;
    ushort tmp[8];
    #pragma unroll
    for (int j = 0; j < 8; ++j) tmp[j] = f2bf(Wconv[(kq*8 + j)*Hh + n]);
    *(uint4*)(wcpk + (long)g*8) = *(uint4*)tmp;
  } else if (g < 16384 + 4096) {         // Wa|Wb granules
    const int gg = g - 16384;
    const int kq = gg >> 6, n = gg & 63;
    const float* W = (n < 32) ? Wa : Wb;
    const int e = n & 31;
    ushort tmp[8];
    #pragma unroll
    for (int j = 0; j < 8; ++j) tmp[j] = f2bf(W[(kq*8 + j)*Ee + e]);
    *(uint4*)(wabpk + (long)gg*8) = *(uint4*)tmp;
  }
}

// ---------------------------------------------------------------------------
// K1: fused normalize + e1|e2 + nfc = nf@Wconv. 256 blocks x 16 rows.
// Double-buffered B staging: one barrier per K-iter.
__global__ __launch_bounds__(256) void norm_e12_nfc(
    const float* __restrict__ nfeat, const ushort* __restrict__ wabpk,
    const ushort* __restrict__ wcpk, const float* __restrict__ be,
    ushort* __restrict__ nfcpk, float* __restrict__ e1, float* __restrict__ e2,
    float* __restrict__ row_sum, float* __restrict__ gr)
{
  const int blk = blockIdx.x;
  const int r0 = blk*16;               // global row base (b*512 + local)
  const int b = r0 >> 9;
  const int t = threadIdx.x;
  const int r = t >> 4;                // local row 0..15
  const int seg = t & 15;              // 32-col segment

  __shared__ ushort As[(63*17 + 15 + 1)*8];   // granule (kq*17 + row)*8
  __shared__ ushort BsA[2][4*64*8];           // Wa|Wb tile granules (dbuf)
  __shared__ ushort BsC[2][4*256*8];          // Wconv tile granules (dbuf)

  // ---- phase 1: load 32 f32/thread, row norm, bf16 granules to LDS ----
  float4 v[8];
  const float* src = nfeat + (long)(r0 + r)*Dd + seg*32;
  #pragma unroll
  for (int i = 0; i < 8; ++i) v[i] = *(const float4*)(src + i*4);
  float s = 0.f;
  #pragma unroll
  for (int i = 0; i < 8; ++i)
    s += v[i].x*v[i].x + v[i].y*v[i].y + v[i].z*v[i].z + v[i].w*v[i].w;
  #pragma unroll
  for (int m = 1; m < 16; m <<= 1) s += __shfl_xor(s, m, 16);
  const float sc = 1.f / fmaxf(sqrtf(s), 1e-12f);
  #pragma unroll
  for (int q = 0; q < 4; ++q) {
    ushort tmp[8];
    const float4 a = v[2*q], bq = v[2*q+1];
    tmp[0]=f2bf(a.x*sc);  tmp[1]=f2bf(a.y*sc);  tmp[2]=f2bf(a.z*sc);  tmp[3]=f2bf(a.w*sc);
    tmp[4]=f2bf(bq.x*sc); tmp[5]=f2bf(bq.y*sc); tmp[6]=f2bf(bq.z*sc); tmp[7]=f2bf(bq.w*sc);
    *(uint4*)(As + ((seg*4 + q)*17 + r)*8) = *(uint4*)tmp;
  }
  if (t < 16) row_sum[r0 + t] = 0.f;
  if (blk == 0) {
    for (int p = t; p < Bsz*Hh; p += 256) gr[p] = 0.f;
  }

  // ---- phase 2: MFMA over K, double-buffered weight staging ----
  const int lane = t & 63, l15 = lane & 15, quad = lane >> 4;
  const int w = t >> 6;                  // wave id 0..3
  const int abq = t >> 6, abn = t & 63;  // Wa|Wb staging map

  f32x4 acc_e = {0.f, 0.f, 0.f, 0.f};
  f32x4 acc_c[4];
  #pragma unroll
  for (int j = 0; j < 4; ++j) acc_c[j] = (f32x4){0.f,0.f,0.f,0.f};

  // stage k=0 into buf 0, then prefetch k=32 into regs
  uint4 pab = *(const uint4*)(wabpk + ((long)abq*64 + abn)*8);
  uint4 pc[4];
  #pragma unroll
  for (int p = 0; p < 4; ++p) {
    const int g = t + p*256;
    pc[p] = *(const uint4*)(wcpk + ((long)(g >> 8)*256 + (g & 255))*8);
  }
  *(uint4*)(BsA[0] + (abq*64 + abn)*8) = pab;
  #pragma unroll
  for (int p = 0; p < 4; ++p) {
    const int g = t + p*256;
    *(uint4*)(BsC[0] + ((g >> 8)*256 + (g & 255))*8) = pc[p];
  }
  {
    pab = *(const uint4*)(wabpk + ((long)(4 + abq)*64 + abn)*8);
    #pragma unroll
    for (int p = 0; p < 4; ++p) {
      const int g = t + p*256;
      pc[p] = *(const uint4*)(wcpk + ((long)(4 + (g >> 8))*256 + (g & 255))*8);
    }
  }

  for (int k0 = 0; k0 < 512; k0 += 32) {
    const int pb = (k0 >> 5) & 1;
    __syncthreads();                     // buf[pb] writes visible; old reads done
    if (k0 + 32 < 512) {
      // stage k0+32 into buf[1-pb] (regs hold it), then prefetch k0+64
      *(uint4*)(BsA[1-pb] + (abq*64 + abn)*8) = pab;
      #pragma unroll
      for (int p = 0; p < 4; ++p) {
        const int g = t + p*256;
        *(uint4*)(BsC[1-pb] + ((g >> 8)*256 + (g & 255))*8) = pc[p];
      }
      if (k0 + 64 < 512) {
        const int kb = (k0 + 64) >> 3;
        pab = *(const uint4*)(wabpk + ((long)(kb + abq)*64 + abn)*8);
        #pragma unroll
        for (int p = 0; p < 4; ++p) {
          const int g = t + p*256;
          pc[p] = *(const uint4*)(wcpk + ((long)(kb + (g >> 8))*256 + (g & 255))*8);
        }
      }
    }
    const bf16x8 af = *(const bf16x8*)(As + (((k0 >> 3) + quad)*17 + l15)*8);
    const bf16x8 bfa = *(const bf16x8*)(BsA[pb] + (quad*64 + w*16 + l15)*8);
    acc_e = __builtin_amdgcn_mfma_f32_16x16x32_bf16(af, bfa, acc_e, 0, 0, 0);
    #pragma unroll
    for (int fn = 0; fn < 4; ++fn) {
      const bf16x8 bfc = *(const bf16x8*)(BsC[pb] + (quad*256 + w*64 + fn*16 + l15)*8);
      acc_c[fn] = __builtin_amdgcn_mfma_f32_16x16x32_bf16(af, bfc, acc_c[fn], 0, 0, 0);
    }
  }

  // ---- epilogue A: e1|e2 (wave w -> cols w*16..+15) ----
  {
    const int col = w*16 + l15;
    #pragma unroll
    for (int rr = 0; rr < 4; ++rr) {
      const int row = r0 + quad*4 + rr;
      if (col < 32) e1[(long)row*Ee + col] = acc_e[rr] + be[col];
      else          e2[(long)row*Ee + (col - 32)] = acc_e[rr];
    }
  }

  // ---- epilogue B: nfc -> k-packed global via LDS transpose ----
  __syncthreads();                       // all frag reads of BsC done
  ushort* tile = BsC[0];                 // [16][260] bf16
  #pragma unroll
  for (int fn = 0; fn < 4; ++fn) {
    const int col = w*64 + fn*16 + l15;
    #pragma unroll
    for (int rr = 0; rr < 4; ++rr)
      tile[(quad*4 + rr)*260 + col] = f2bf(acc_c[fn][rr]);
  }
  __syncthreads();
  #pragma unroll
  for (int p = 0; p < 2; ++p) {
    const int g = t + p*256;
    const int oct = g >> 8, c = g & 255;
    ushort tmp[8];
    #pragma unroll
    for (int j = 0; j < 8; ++j) tmp[j] = tile[(oct*8 + j)*260 + c];
    const long og = ((r0 & 511) >> 3) + oct;     // node-octet within batch
    *(uint4*)(nfcpk + ((long)b*16384 + og*256 + c)*8) = *(uint4*)tmp;
  }
}

// ---------------------------------------------------------------------------
// K2: tiled edge scoring. R9 retile: block = (b, 16-row i-tile, 64-col
// j-tile), grid 8x32x8 = 2048 blocks (8/CU). Thread = 1 row x 4 cols.
// adjs loaded before the k-loop (latency hidden under compute). l0 summed
// to a per-block partial (no same-address atomics).
__global__ __launch_bounds__(256) void edge_kernel(
    const float* __restrict__ e1, const float* __restrict__ e2,
    const float* __restrict__ W2e, const float* __restrict__ b2e,
    const float* __restrict__ adjs, float* __restrict__ out_wadj,
    ushort* __restrict__ wadj_b, float* __restrict__ row_sum,
    float* __restrict__ l0_part)
{
  const int b  = blockIdx.z;
  const int i0 = blockIdx.y * 16;
  const int j0 = blockIdx.x * 64;
  const int t  = threadIdx.x;

  __shared__ float e2s[32*68];           // [k][j], pad 68
  __shared__ float l0red[4];

  // stage e2 tile: 64 j-rows x 32 k (512 float4)
  #pragma unroll
  for (int itr = 0; itr < 2; ++itr) {
    const int idx = t + itr*256;
    const int kq = idx & 7, jg = idx >> 3;
    const float4 v = *(const float4*)(e2 + ((long)(b*Nn + j0 + jg))*Ee + kq*4);
    e2s[(kq*4+0)*68 + jg] = v.x;
    e2s[(kq*4+1)*68 + jg] = v.y;
    e2s[(kq*4+2)*68 + jg] = v.z;
    e2s[(kq*4+3)*68 + jg] = v.w;
  }

  const int row   = t >> 4;              // local i 0..15
  const int jslot = t & 15;              // 4 cols each
  const int i  = i0 + row;
  const int jl = jslot*4;

  // early adjs load: latency hides under e1 load + k-loop
  const float4 av = *(const float4*)(adjs + ((long)(b*Nn + i))*Nn + j0 + jl);

  float e1f[32], w2f[32];
  #pragma unroll
  for (int q = 0; q < 8; ++q) {
    *(float4*)(&e1f[q*4]) = *(const float4*)(e1 + ((long)(b*Nn + i))*Ee + q*4);
    *(float4*)(&w2f[q*4]) = *(const float4*)(W2e + q*4);
  }
  const float b2 = b2e[0];
  __syncthreads();

  float acc[4] = {0.f, 0.f, 0.f, 0.f};
  #pragma unroll
  for (int k = 0; k < 32; ++k) {
    const float4 va = *(const float4*)(e2s + k*68 + jl);
    const float w = w2f[k];
    const float ea = e1f[k];
    acc[0] += fmaxf(ea+va.x, 0.f)*w;
    acc[1] += fmaxf(ea+va.y, 0.f)*w;
    acc[2] += fmaxf(ea+va.z, 0.f)*w;
    acc[3] += fmaxf(ea+va.w, 0.f)*w;
  }

  float rs = 0.f, l0acc = 0.f;
  float wv[4];
  #pragma unroll
  for (int c = 0; c < 4; ++c) {
    const float logA = acc[c] + b2;
    const float e = expf(-logA);              // one transcendental
    const float sg = 1.f/(1.f + e);
    const float gate = fminf(fmaxf(sg*1.2f - 0.1f, 0.f), 1.f);
    const float a = (c==0)?av.x:(c==1)?av.y:(c==2)?av.z:av.w;
    const float w = gate*a*a;
    wv[c] = w;
    rs += w;
    l0acc += 1.f/(1.f + 0.20543832f*e);       // sigma(logA + 1.58261088)
  }
  {
    ushort4 bw;
    bw.x = f2bf(wv[0]); bw.y = f2bf(wv[1]); bw.z = f2bf(wv[2]); bw.w = f2bf(wv[3]);
    *(ushort4*)(wadj_b + ((long)(b*Nn + i))*Nn + j0 + jl) = bw;
    float* outrow = out_wadj + ((long)(b*Nn + i))*Nn + j0 + jl;
    outrow[0] = wv[0]; outrow[1] = wv[1];     // out+17: 4B-aligned only
    outrow[2] = wv[2]; outrow[3] = wv[3];
  }

  // rs: reduce over the 16 jslots of this row (within-wave, width 16)
  #pragma unroll
  for (int m = 1; m < 16; m <<= 1) rs += __shfl_xor(rs, m, 16);
  if (jslot == 0) atomicAdd(&row_sum[b*Nn + i], rs);

  // l0: wave reduce -> block reduce -> per-block partial (no atomics)
  #pragma unroll
  for (int m = 1; m < 64; m <<= 1) l0acc += __shfl_xor(l0acc, m, 64);
  if ((t & 63) == 0) l0red[t >> 6] = l0acc;
  __syncthreads();
  if (t == 0)
    l0_part[((long)blockIdx.z*32 + blockIdx.y)*8 + blockIdx.x] =
        l0red[0] + l0red[1] + l0red[2] + l0red[3];
}

// ---------------------------------------------------------------------------
// K3: gemm_pool. h_tile = relu((wadj/rs)@nfc + bconv), attention-pool tile
// into gr. Double-buffered staging: one barrier per K-iter.
// Softmax via wave shuffles — 2 barriers.
__global__ __launch_bounds__(256) void gemm_pool(
    const ushort* __restrict__ wadjb, const ushort* __restrict__ nfcpk,
    const float* __restrict__ row_sum, const float* __restrict__ masks,
    const float* __restrict__ bconv, float* __restrict__ gr)
{
  const int bb = blockIdx.z;
  const int m0 = blockIdx.y*64, n0 = blockIdx.x*64;
  const int t = threadIdx.x;
  const int lane = t & 63, l15 = lane & 15, quad = lane >> 4;
  const int wv = t >> 6, wr = wv & 1, wc = wv >> 1;

  __shared__ ushort As[2][259*8];            // granule (akq*65 + m)*8 (dbuf)
  __shared__ ushort Bs[2][256*8];            // granule (bkq*64 + n)*8 (dbuf)
  __shared__ float ptile[64*65];             // weighted h tile
  __shared__ float red[8];
  __shared__ float attn_s[64];

  const ushort* Ab = wadjb + (long)bb*262144;
  const ushort* Bb = nfcpk + (long)bb*131072;
  const int am = t >> 2, akq = t & 3;
  const int bn = t & 63, bkq = t >> 6;

  f32x4 acc[2][2];
  #pragma unroll
  for (int i = 0; i < 2; ++i)
    #pragma unroll
    for (int j = 0; j < 2; ++j) acc[i][j] = (f32x4){0.f,0.f,0.f,0.f};

  // stage k=0 into buf0, prefetch k=32
  uint4 ra = *(const uint4*)(Ab + (long)(m0+am)*512 + akq*8);
  uint4 rb = *(const uint4*)(Bb + ((long)bkq*256 + n0 + bn)*8);
  *(uint4*)(As[0] + (akq*65 + am)*8) = ra;
  *(uint4*)(Bs[0] + (bkq*64 + bn)*8) = rb;
  ra = *(const uint4*)(Ab + (long)(m0+am)*512 + 32 + akq*8);
  rb = *(const uint4*)(Bb + ((long)(4 + bkq)*256 + n0 + bn)*8);

  for (int k0 = 0; k0 < 512; k0 += 32) {
    const int pb = (k0 >> 5) & 1;
    __syncthreads();
    if (k0 + 32 < 512) {
      *(uint4*)(As[1-pb] + (akq*65 + am)*8) = ra;
      *(uint4*)(Bs[1-pb] + (bkq*64 + bn)*8) = rb;
      if (k0 + 64 < 512) {
        ra = *(const uint4*)(Ab + (long)(m0+am)*512 + (k0+64) + akq*8);
        rb = *(const uint4*)(Bb + ((long)(((k0+64) >> 3) + bkq)*256 + n0 + bn)*8);
      }
    }
    bf16x8 af[2], bfr[2];
    #pragma unroll
    for (int i = 0; i < 2; ++i)
      af[i] = *(const bf16x8*)(As[pb] + (quad*65 + wr*32 + i*16 + l15)*8);
    #pragma unroll
    for (int j = 0; j < 2; ++j)
      bfr[j] = *(const bf16x8*)(Bs[pb] + (quad*64 + wc*32 + j*16 + l15)*8);
    #pragma unroll
    for (int i = 0; i < 2; ++i)
      #pragma unroll
      for (int j = 0; j < 2; ++j)
        acc[i][j] = __builtin_amdgcn_mfma_f32_16x16x32_bf16(
            af[i], bfr[j], acc[i][j], 0, 0, 0);
  }
  __syncthreads();

  // attention softmax over this batch's masked degrees (block-redundant):
  // wave-level shuffle reductions, 2 barriers total.
  {
    const float mk0 = masks[bb*Nn + t], mk1 = masks[bb*Nn + t + 256];
    const float lv0 = (mk0 > 0.f) ? row_sum[bb*Nn + t] : -1e9f;
    const float lv1 = (mk1 > 0.f) ? row_sum[bb*Nn + t + 256] : -1e9f;
    float m = fmaxf(lv0, lv1);
    #pragma unroll
    for (int s = 1; s < 64; s <<= 1) m = fmaxf(m, __shfl_xor(m, s, 64));
    if (lane == 0) red[wv] = m;
    __syncthreads();
    const float mx = fmaxf(fmaxf(red[0], red[1]), fmaxf(red[2], red[3]));
    float sm = expf(lv0 - mx) + expf(lv1 - mx);
    #pragma unroll
    for (int s = 1; s < 64; s <<= 1) sm += __shfl_xor(sm, s, 64);
    if (lane == 0) red[4 + wv] = sm;
    __syncthreads();
    const float sinv = 1.f/(red[4] + red[5] + red[6] + red[7]);
    if (t < 64) {
      const int node = m0 + t;
      const float mm = masks[bb*Nn + node];
      const float lv = (mm > 0.f) ? row_sum[bb*Nn + node] : -1e9f;
      attn_s[t] = expf(lv - mx)*sinv;
    }
    __syncthreads();
  }

  // epilogue: h = relu(acc/rs + bias), weight by attn, stash in LDS
  #pragma unroll
  for (int i = 0; i < 2; ++i) {
    #pragma unroll
    for (int j = 0; j < 2; ++j) {
      const int lcol = wc*32 + j*16 + l15;
      const float bias = bconv[n0 + lcol];
      #pragma unroll
      for (int rr = 0; rr < 4; ++rr) {
        const int lrow = wr*32 + i*16 + quad*4 + rr;
        const int row = m0 + lrow;
        const float scl = 1.f/(row_sum[bb*Nn + row] + 1e-8f);
        const float hv = fmaxf(acc[i][j][rr]*scl + bias, 0.f);
        ptile[lrow*65 + lcol] = hv * attn_s[lrow];
      }
    }
  }
  __syncthreads();
  if (t < 64) {
    float s = 0.f;
    #pragma unroll 4
    for (int rr = 0; rr < 64; ++rr) s += ptile[rr*65 + t];
    atomicAdd(&gr[bb*Hh + n0 + t], s);
  }
}

// ---------------------------------------------------------------------------
// K4: classifier head + spectral norm + losses. Single block.
// z-GEMM via register-preloaded W1c (32 independent dwordx4/thread).
// R9: also reduces the 2048 edge-block l0 partials.
__global__ __launch_bounds__(256) void classifier_kernel(
    const float* __restrict__ gr, const float* __restrict__ W1c,
    const float* __restrict__ b1c, const float* __restrict__ ln_g,
    const float* __restrict__ ln_b, const float* __restrict__ W2c,
    const float* __restrict__ b2c, const float* __restrict__ u_sn,
    const int* __restrict__ labels, const float* __restrict__ l0_part,
    float* __restrict__ out)
{
  const int t = threadIdx.x;
  const int og = t & 31;               // output col group (4 cols)
  const int dr = t >> 5;               // d-group (32 d's)

  __shared__ float grs[2048];
  __shared__ float part[8][8][128];    // [dgroup][batch][col] 32 KB
  __shared__ float z[8][128];
  __shared__ float mu_s[8], ri_s[8];
  __shared__ float snpart[6];
  __shared__ float l0w[4];
  __shared__ float sinv_s;
  __shared__ float lg[16];

  // ---- issue all W1c loads up front: 32 independent dwordx4 per thread ----
  float4 w[32];
  const float* wp = W1c + (long)dr*32*128 + og*4;
  #pragma unroll
  for (int i = 0; i < 32; ++i) w[i] = *(const float4*)(wp + i*128);

  // gr -> LDS + l0 partial sum (overlap with W1c loads in flight)
  #pragma unroll
  for (int p = 0; p < 8; ++p) grs[t + p*256] = gr[t + p*256];
  float l0t = 0.f;
  #pragma unroll
  for (int p = 0; p < 8; ++p) l0t += l0_part[t + p*256];
  #pragma unroll
  for (int m = 1; m < 64; m <<= 1) l0t += __shfl_xor(l0t, m, 64);
  if ((t & 63) == 0) l0w[t >> 6] = l0t;
  __syncthreads();

  // ---- partial z: all 8 batches reuse each W1c element ----
  float4 acc[8];
  #pragma unroll
  for (int b = 0; b < 8; ++b) acc[b] = (float4){0.f,0.f,0.f,0.f};
  #pragma unroll
  for (int i = 0; i < 32; ++i) {
    const int d = dr*32 + i;
    #pragma unroll
    for (int b = 0; b < 8; ++b) {
      const float g = grs[b*256 + d];
      acc[b].x += g*w[i].x; acc[b].y += g*w[i].y;
      acc[b].z += g*w[i].z; acc[b].w += g*w[i].w;
    }
  }
  #pragma unroll
  for (int b = 0; b < 8; ++b)
    *(float4*)(&part[dr][b][og*4]) = acc[b];
  __syncthreads();

  // ---- reduce d-groups, bias, relu -> z ----
  #pragma unroll
  for (int p = 0; p < 4; ++p) {
    const int idx = t + p*256;
    const int b = idx >> 7, o = idx & 127;
    float s = b1c[o];
    #pragma unroll
    for (int d2 = 0; d2 < 8; ++d2) s += part[d2][b][o];
    z[b][o] = fmaxf(s, 0.f);
  }
  __syncthreads();

  // LN stats: 32 lanes per batch, shuffle reduce
  {
    const int b = t >> 5, g = t & 31;
    const float4 zv = *(const float4*)(&z[b][g*4]);
    float s1 = zv.x + zv.y + zv.z + zv.w;
    #pragma unroll
    for (int m = 1; m < 32; m <<= 1) s1 += __shfl_xor(s1, m, 32);
    const float mu = s1*(1.f/128.f);
    float s2 = (zv.x-mu)*(zv.x-mu) + (zv.y-mu)*(zv.y-mu)
             + (zv.z-mu)*(zv.z-mu) + (zv.w-mu)*(zv.w-mu);
    #pragma unroll
    for (int m = 1; m < 32; m <<= 1) s2 += __shfl_xor(s2, m, 32);
    if (g == 0) { mu_s[b] = mu; ri_s[b] = rsqrtf(s2*(1.f/128.f) + 1e-5f); }
  }

  // spectral norm: one fused 3-value reduction over the 128 rows of W2c
  if (t < 128) {
    const float w0 = W2c[2*t], w1 = W2c[2*t+1];
    const float vt = w0*u_sn[0] + w1*u_sn[1];
    float svv = vt*vt, sa = vt*w0, sb = vt*w1;
    #pragma unroll
    for (int m = 1; m < 64; m <<= 1) {
      svv += __shfl_xor(svv, m, 64);
      sa  += __shfl_xor(sa , m, 64);
      sb  += __shfl_xor(sb , m, 64);
    }
    if ((t & 63) == 0) {
      const int wd = t >> 6;
      snpart[wd*3+0] = svv; snpart[wd*3+1] = sa; snpart[wd*3+2] = sb;
    }
  }
  __syncthreads();                 // covers mu_s/ri_s + snpart[]
  if (t == 0) {
    const float svv = snpart[0] + snpart[3];
    const float sa  = snpart[1] + snpart[4];
    const float sb  = snpart[2] + snpart[5];
    const float vninv = 1.f/fmaxf(sqrtf(svv), 1e-12f);
    const float u20 = sa*vninv, u21 = sb*vninv;
    const float uninv = 1.f/fmaxf(sqrtf(u20*u20 + u21*u21), 1e-12f);
    const float u2n0 = u20*uninv, u2n1 = u21*uninv;
    const float sigma = vninv*(u2n0*sa + u2n1*sb);
    sinv_s = 1.f/sigma;
  }
  __syncthreads();

  // logits: 16 groups of 16 lanes, each group owns one (b,c)
  {
    const float sinv = sinv_s;
    const int grp = t >> 4, g = t & 15;
    const int b = grp >> 1, c = grp & 1;
    const float mu = mu_s[b], ri = ri_s[b];
    float acc2 = 0.f;
    #pragma unroll
    for (int j = 0; j < 8; ++j) {
      const int o = g*8 + j;
      const float zln = (z[b][o]-mu)*ri*ln_g[o] + ln_b[o];
      acc2 += zln*W2c[2*o + c];
    }
    #pragma unroll
    for (int m = 1; m < 16; m <<= 1) acc2 += __shfl_xor(acc2, m, 16);
    if (g == 0) {
      const float lgv = acc2*sinv + b2c[c];
      lg[grp] = lgv;
      out[grp] = lgv;
    }
  }
  __syncthreads();
  if (t == 0) {
    float closs = 0.f;
    #pragma unroll
    for (int b = 0; b < 8; ++b) {
      const float a0 = lg[2*b], a1 = lg[2*b+1];
      const float m = fmaxf(a0, a1);
      const float lse = m + logf(expf(a0-m) + expf(a1-m));
      closs += lse - lg[2*b + labels[b]];
    }
    const float l0 = l0w[0] + l0w[1] + l0w[2] + l0w[3];
    out[16] = closs*(1.f/8.f) + 0.01f*l0;
  }
}

extern "C" void kernel_launch(void* const* d_in, const int* in_sizes, int n_in,
                              void* d_out, int out_size, void* d_ws, size_t ws_size,
                              hipStream_t stream) {
  const float* node_feat = (const float*)d_in[0];
  const int*   labels    = (const int*)d_in[1];
  const float* adjs      = (const float*)d_in[2];
  const float* masks     = (const float*)d_in[3];
  const float* Wa        = (const float*)d_in[4];
  const float* Wb        = (const float*)d_in[5];
  const float* be        = (const float*)d_in[6];
  const float* W2e       = (const float*)d_in[7];
  const float* b2e       = (const float*)d_in[8];
  const float* Wconv     = (const float*)d_in[9];
  const float* bconv     = (const float*)d_in[10];
  const float* W1c       = (const float*)d_in[11];
  const float* b1c       = (const float*)d_in[12];
  const float* ln_g      = (const float*)d_in[13];
  const float* ln_b      = (const float*)d_in[14];
  const float* W2c       = (const float*)d_in[15];
  const float* b2c       = (const float*)d_in[16];
  const float* u_sn      = (const float*)d_in[17];

  float* out = (float*)d_out;
  float* ws  = (float*)d_ws;
  ushort* nfcpk  = (ushort*)(ws + WS_NFCPK);
  float*  e1     = ws + WS_E1;
  float*  e2     = ws + WS_E2;
  ushort* wadjb  = (ushort*)(ws + WS_WADJB);
  float*  row_sum= ws + WS_RS;
  float*  gr     = ws + WS_GR;
  ushort* wabpk  = (ushort*)(ws + WS_WABPK);
  ushort* wcpk   = (ushort*)(ws + WS_WCPK);
  float*  l0p    = ws + WS_L0P;

  pack_weights<<<80, 256, 0, stream>>>(Wconv, Wa, Wb, wcpk, wabpk);
  norm_e12_nfc<<<256, 256, 0, stream>>>(node_feat, wabpk, wcpk, be, nfcpk,
                                        e1, e2, row_sum, gr);
  edge_kernel<<<dim3(Nn/64, Nn/16, Bsz), 256, 0, stream>>>(
      e1, e2, W2e, b2e, adjs, out + 17, wadjb, row_sum, l0p);
  gemm_pool<<<dim3(Hh/64, Nn/64, Bsz), 256, 0, stream>>>(
      wadjb, nfcpk, row_sum, masks, bconv, gr);
  classifier_kernel<<<1, 256, 0, stream>>>(gr, W1c, b1c, ln_g, ln_b, W2c, b2c,
                                           u_sn, labels, l0p, out);
}